// Round 6
// baseline (751.129 us; speedup 1.0000x reference)
//
#include <hip/hip_runtime.h>
#include <hip/hip_bf16.h>
#include <math.h>

#define TOK   12608      // 64*197
#define DMODEL 768
#define QKVN  2304
#define HID   3072
#define NH    12
#define SEQ   197
#define SPAD  256        // padded t dimension
#define SROW  208        // padded s rows in P
#define NBH   768        // 64*12

typedef __attribute__((ext_vector_type(8))) __bf16 bf16x8;
typedef __attribute__((ext_vector_type(4))) float  f32x4;

__device__ __forceinline__ unsigned short f2b(float f){
  unsigned u = __builtin_bit_cast(unsigned, f);
  u += 0x7FFFu + ((u >> 16) & 1u);
  return (unsigned short)(u >> 16);
}
__device__ __forceinline__ float b2f(unsigned short h){
  unsigned u = ((unsigned)h) << 16;
  return __builtin_bit_cast(float, u);
}

#define GLD16(g, l) __builtin_amdgcn_global_load_lds( \
    (const __attribute__((address_space(1))) void*)(g), \
    (__attribute__((address_space(3))) void*)(l), 16, 0, 0)

// ---------------- fp32 -> bf16 elementwise ----------------
__global__ void cvt_x(const float* __restrict__ x, unsigned short* __restrict__ xb, int n){
  int idx = (blockIdx.x * blockDim.x + threadIdx.x) * 4;
  if (idx < n){
    float4 v = *reinterpret_cast<const float4*>(x + idx);
    ushort4 o; o.x = f2b(v.x); o.y = f2b(v.y); o.z = f2b(v.z); o.w = f2b(v.w);
    *reinterpret_cast<ushort4*>(xb + idx) = o;
  }
}

// ---------------- weight transpose + convert: W[K][N] f32 -> Wt[N][K] bf16 ----------------
__global__ void wt_t(const float* __restrict__ W, unsigned short* __restrict__ Wt, int K, int N){
  __shared__ float tile[32][33];
  int k0 = blockIdx.y * 32, n0 = blockIdx.x * 32;
  int tx = threadIdx.x & 31, ty = threadIdx.x >> 5;   // 256 threads: ty 0..7
#pragma unroll
  for (int i = 0; i < 32; i += 8)
    tile[ty + i][tx] = W[(size_t)(k0 + ty + i) * N + n0 + tx];
  __syncthreads();
#pragma unroll
  for (int i = 0; i < 32; i += 8)
    Wt[(size_t)(n0 + ty + i) * K + k0 + tx] = f2b(tile[tx][ty + i]);
}

__global__ void cat_bias(const float* __restrict__ a, const float* __restrict__ b,
                         const float* __restrict__ c, float* __restrict__ o){
  int i = blockIdx.x * blockDim.x + threadIdx.x;
  if (i < 768) o[i] = a[i];
  else if (i < 1536) o[i] = b[i - 768];
  else if (i < 2304) o[i] = c[i - 1536];
}

// ---------------- main NT GEMM: C[M][N] = act(A[M,K] @ Wt[N,K]^T + bias) ----------------
// 128x128 tile, BK=32, 4 waves (2x2), 16x16x32 bf16 MFMA, global_load_lds staging.
template<int ACT>
__global__ __launch_bounds__(256)
void gemm_nt(const unsigned short* __restrict__ A,
             const unsigned short* __restrict__ Bt,
             const float* __restrict__ bias,
             unsigned short* __restrict__ C,
             int M, int N, int K)
{
  __shared__ unsigned short As[128 * 32];
  __shared__ unsigned short Bs[128 * 32];
  const int nb = N >> 7;
  const int bm = blockIdx.x / nb;
  const int bn = blockIdx.x - bm * nb;
  const int m0 = bm << 7, n0 = bn << 7;
  const int tid = threadIdx.x;
  const int lane = tid & 63;
  const int wid = tid >> 6;

  // staging: chunk c = tid covers row r=tid>>2, k-part (tid&3)*8 (16B)
  const int r  = tid >> 2;
  const int kk = (tid & 3) << 3;
  const unsigned short* gA1 = A  + (size_t)min(m0 + r,      M - 1) * K + kk;
  const unsigned short* gA2 = A  + (size_t)min(m0 + r + 64, M - 1) * K + kk;
  const unsigned short* gB1 = Bt + (size_t)(n0 + r)      * K + kk;
  const unsigned short* gB2 = Bt + (size_t)(n0 + r + 64) * K + kk;

  char* ldsA = (char*)As + wid * 1024;
  char* ldsB = (char*)Bs + wid * 1024;

  const int fr = lane & 15;
  const int kg = (lane >> 4) << 3;
  const int wm = (wid >> 1) << 6;
  const int wn = (wid & 1) << 6;

  f32x4 acc[4][4] = {};

  for (int kt = 0; kt < K; kt += 32){
    __syncthreads();
    GLD16(gA1 + kt, ldsA);
    GLD16(gA2 + kt, ldsA + 4096);
    GLD16(gB1 + kt, ldsB);
    GLD16(gB2 + kt, ldsB + 4096);
    __syncthreads();

    bf16x8 af[4], bfv[4];
#pragma unroll
    for (int i = 0; i < 4; i++)
      af[i]  = *reinterpret_cast<const bf16x8*>(&As[(wm + i * 16 + fr) * 32 + kg]);
#pragma unroll
    for (int i = 0; i < 4; i++)
      bfv[i] = *reinterpret_cast<const bf16x8*>(&Bs[(wn + i * 16 + fr) * 32 + kg]);
#pragma unroll
    for (int mi = 0; mi < 4; mi++)
#pragma unroll
      for (int ni = 0; ni < 4; ni++)
        acc[mi][ni] = __builtin_amdgcn_mfma_f32_16x16x32_bf16(af[mi], bfv[ni], acc[mi][ni], 0, 0, 0);
  }

  const int rbase = m0 + wm + ((lane >> 4) << 2);
#pragma unroll
  for (int ni = 0; ni < 4; ni++){
    const int cc = n0 + wn + ni * 16 + fr;
    const float bv = bias[cc];
#pragma unroll
    for (int mi = 0; mi < 4; mi++){
      const int rr0 = rbase + mi * 16;
#pragma unroll
      for (int j = 0; j < 4; j++){
        int rr = rr0 + j;
        if (rr < M){
          float v = acc[mi][ni][j] + bv;
          if (ACT == 1) v = 0.5f * v * (1.0f + erff(v * 0.70710678118f));
          C[(size_t)rr * N + cc] = f2b(v);
        }
      }
    }
  }
}

// ---------------- attention scores: P[bh][s][t] = (q . k) * 0.125, bf16 ----------------
// grid = NBH * 7(mtiles of 32) * 2(ntiles of 128); 4 waves 2x2, wave tile 16x64, K=64
__global__ __launch_bounds__(256)
void attn_scores(const unsigned short* __restrict__ qkv, unsigned short* __restrict__ P)
{
  const int gid = blockIdx.x;
  const int nt = gid & 1;
  const int mt = (gid >> 1) % 7;
  const int bh = gid / 14;
  const int b = bh / NH, h = bh - b * NH;
  const int lane = threadIdx.x & 63, wid = threadIdx.x >> 6;
  const int m0 = mt * 32 + (wid >> 1) * 16;
  const int n0 = nt * 128 + (wid & 1) * 64;
  const size_t qbase = (size_t)b * SEQ * QKVN + h * 64;
  const size_t kbase = qbase + 768;
  const int fr = lane & 15;
  const int kg = (lane >> 4) << 3;
  const int ar = min(m0 + fr, SEQ - 1);

  f32x4 acc[4] = {};
#pragma unroll
  for (int ks = 0; ks < 64; ks += 32){
    bf16x8 af = *reinterpret_cast<const bf16x8*>(&qkv[qbase + (size_t)ar * QKVN + ks + kg]);
#pragma unroll
    for (int ni = 0; ni < 4; ni++){
      int t = min(n0 + ni * 16 + fr, SEQ - 1);
      bf16x8 bv = *reinterpret_cast<const bf16x8*>(&qkv[kbase + (size_t)t * QKVN + ks + kg]);
      acc[ni] = __builtin_amdgcn_mfma_f32_16x16x32_bf16(af, bv, acc[ni], 0, 0, 0);
    }
  }
  const int rbase = m0 + ((lane >> 4) << 2);
#pragma unroll
  for (int ni = 0; ni < 4; ni++){
    int cc = n0 + ni * 16 + fr;
#pragma unroll
    for (int j = 0; j < 4; j++){
      int rr = rbase + j;
      if (rr < SEQ)
        P[((size_t)bh * SROW + rr) * SPAD + cc] = f2b(acc[ni][j] * 0.125f);
    }
  }
}

// ---------------- softmax: one wave per row, 256 cols (197 valid) ----------------
__global__ __launch_bounds__(256)
void softmax_k(unsigned short* __restrict__ P)
{
  const int idx = blockIdx.x * 4 + (threadIdx.x >> 6);
  const int bh = idx / SEQ;
  const int s  = idx - bh * SEQ;
  unsigned short* p = P + ((size_t)bh * SROW + s) * SPAD;
  const int lane = threadIdx.x & 63;
  float v[4];
  ushort4 u = *reinterpret_cast<const ushort4*>(p + lane * 4);
  v[0] = b2f(u.x); v[1] = b2f(u.y); v[2] = b2f(u.z); v[3] = b2f(u.w);
  float m = -1e30f;
#pragma unroll
  for (int j = 0; j < 4; j++){
    if (lane * 4 + j < SEQ) m = fmaxf(m, v[j]); else v[j] = -1e30f;
  }
#pragma unroll
  for (int o = 32; o > 0; o >>= 1) m = fmaxf(m, __shfl_xor(m, o));
  float sum = 0.f;
#pragma unroll
  for (int j = 0; j < 4; j++){ v[j] = __expf(v[j] - m); sum += v[j]; }
#pragma unroll
  for (int o = 32; o > 0; o >>= 1) sum += __shfl_xor(sum, o);
  const float inv = 1.0f / sum;
  ushort4 o4;
  o4.x = f2b(v[0] * inv); o4.y = f2b(v[1] * inv);
  o4.z = f2b(v[2] * inv); o4.w = f2b(v[3] * inv);
  *reinterpret_cast<ushort4*>(p + lane * 4) = o4;
}

// ---------------- V transpose per head: VT[bh][d][t] (t padded 256, zeros) ----------------
__global__ __launch_bounds__(256)
void vtrans(const unsigned short* __restrict__ qkv, unsigned short* __restrict__ VT)
{
  const int bh = blockIdx.x;
  const int b = bh / NH, h = bh - b * NH;
  __shared__ unsigned short t[SROW][66];
  const size_t vbase = (size_t)b * SEQ * QKVN + 1536 + h * 64;
  const int lane = threadIdx.x & 63, wid = threadIdx.x >> 6;
  for (int s = wid; s < SROW; s += 4){
    unsigned short val = 0;
    if (s < SEQ) val = qkv[vbase + (size_t)s * QKVN + lane];
    t[s][lane] = val;
  }
  __syncthreads();
  unsigned short* o = VT + (size_t)bh * 64 * SPAD;
  const int tid = threadIdx.x;
#pragma unroll
  for (int i = 0; i < 64; i++){
    int idx = tid + i * 256;
    int d = idx >> 8, tt = idx & 255;
    o[idx] = (tt < SROW) ? t[tt][d] : (unsigned short)0;
  }
}

// ---------------- ctx: C[b,s,(h,d)] = P[bh] @ V[bh]  (M=197,N=64,K=256) ----------------
// grid = NBH * 4(mtiles of 64); wave w handles rows m0+w*16, all 64 cols
__global__ __launch_bounds__(256)
void attn_ctx(const unsigned short* __restrict__ P,
              const unsigned short* __restrict__ VT,
              unsigned short* __restrict__ ctx)
{
  const int mt = blockIdx.x & 3;
  const int bh = blockIdx.x >> 2;
  const int b = bh / NH, h = bh - b * NH;
  const int lane = threadIdx.x & 63, wid = threadIdx.x >> 6;
  const int m0 = mt * 64 + wid * 16;
  const unsigned short* Pr = P  + (size_t)bh * SROW * SPAD;
  const unsigned short* Vr = VT + (size_t)bh * 64 * SPAD;
  const int fr = lane & 15;
  const int kg = (lane >> 4) << 3;
  const int ar = min(m0 + fr, SEQ - 1);

  f32x4 acc[4] = {};
#pragma unroll
  for (int ks = 0; ks < SPAD; ks += 32){
    bf16x8 af = *reinterpret_cast<const bf16x8*>(&Pr[(size_t)ar * SPAD + ks + kg]);
#pragma unroll
    for (int ni = 0; ni < 4; ni++){
      bf16x8 bv = *reinterpret_cast<const bf16x8*>(&Vr[(size_t)(ni * 16 + fr) * SPAD + ks + kg]);
      acc[ni] = __builtin_amdgcn_mfma_f32_16x16x32_bf16(af, bv, acc[ni], 0, 0, 0);
    }
  }
  const int rbase = m0 + ((lane >> 4) << 2);
#pragma unroll
  for (int ni = 0; ni < 4; ni++){
    int d = ni * 16 + fr;
#pragma unroll
    for (int j = 0; j < 4; j++){
      int rr = rbase + j;
      if (rr < SEQ)
        ctx[((size_t)b * SEQ + rr) * DMODEL + h * 64 + d] = f2b(acc[ni][j]);
    }
  }
}

// ---------------- residual + LayerNorm: out = res + LN(y)*g + be ----------------
// one wave per row (64 lanes x 12 elems = 768)
// RESF32: residual input is f32.  OUTF32: write f32 output (final kernel -> d_out).
template<int RESF32, int OUTF32>
__global__ __launch_bounds__(256)
void ln_res(const unsigned short* __restrict__ y,
            const void* __restrict__ res,
            const float* __restrict__ g,
            const float* __restrict__ be,
            void* __restrict__ out)
{
  const int row = blockIdx.x * 4 + (threadIdx.x >> 6);
  const int lane = threadIdx.x & 63;
  const int c0 = lane * 12;
  const unsigned short* yr = y + (size_t)row * DMODEL + c0;
  float v[12];
#pragma unroll
  for (int i = 0; i < 3; i++){
    ushort4 u = *reinterpret_cast<const ushort4*>(yr + i * 4);
    v[i*4+0] = b2f(u.x); v[i*4+1] = b2f(u.y); v[i*4+2] = b2f(u.z); v[i*4+3] = b2f(u.w);
  }
  float s = 0.f;
#pragma unroll
  for (int i = 0; i < 12; i++) s += v[i];
#pragma unroll
  for (int o = 32; o > 0; o >>= 1) s += __shfl_xor(s, o);
  const float mu = s * (1.0f / 768.0f);
  float vs = 0.f;
#pragma unroll
  for (int i = 0; i < 12; i++){ float d = v[i] - mu; vs += d * d; }
#pragma unroll
  for (int o = 32; o > 0; o >>= 1) vs += __shfl_xor(vs, o);
  const float rstd = rsqrtf(vs * (1.0f / 768.0f) + 1e-6f);
  float ov[12];
#pragma unroll
  for (int i = 0; i < 12; i++){
    float rv;
    if (RESF32) rv = ((const float*)res)[(size_t)row * DMODEL + c0 + i];
    else        rv = b2f(((const unsigned short*)res)[(size_t)row * DMODEL + c0 + i]);
    ov[i] = (v[i] - mu) * rstd * g[c0 + i] + be[c0 + i] + rv;
  }
  if (OUTF32){
    float* o = (float*)out + (size_t)row * DMODEL + c0;
#pragma unroll
    for (int i = 0; i < 3; i++)
      *reinterpret_cast<float4*>(o + i * 4) = *reinterpret_cast<float4*>(&ov[i * 4]);
  } else {
    unsigned short* o = (unsigned short*)out + (size_t)row * DMODEL + c0;
    unsigned short ob[12];
#pragma unroll
    for (int i = 0; i < 12; i++) ob[i] = f2b(ov[i]);
#pragma unroll
    for (int i = 0; i < 3; i++)
      *reinterpret_cast<ushort4*>(o + i * 4) = *reinterpret_cast<ushort4*>(&ob[i * 4]);
  }
}

// ---------------- host ----------------
extern "C" void kernel_launch(void* const* d_in, const int* in_sizes, int n_in,
                              void* d_out, int out_size, void* d_ws, size_t ws_size,
                              hipStream_t stream)
{
  const float* x   = (const float*)d_in[0];
  const float* Wq  = (const float*)d_in[1];
  const float* bq  = (const float*)d_in[2];
  const float* Wk  = (const float*)d_in[3];
  const float* bk  = (const float*)d_in[4];
  const float* Wv  = (const float*)d_in[5];
  const float* bv  = (const float*)d_in[6];
  const float* Wo  = (const float*)d_in[7];
  const float* bo  = (const float*)d_in[8];
  const float* W1  = (const float*)d_in[9];
  const float* b1  = (const float*)d_in[10];
  const float* W2  = (const float*)d_in[11];
  const float* b2  = (const float*)d_in[12];
  const float* g1  = (const float*)d_in[13];
  const float* be1 = (const float*)d_in[14];
  const float* g2  = (const float*)d_in[15];
  const float* be2 = (const float*)d_in[16];

  char* w = (char*)d_ws;
  size_t off = 0;
  auto alloc = [&](size_t bytes){ void* p = w + off; off = (off + bytes + 255) & ~(size_t)255; return p; };
  unsigned short* wqkvt = (unsigned short*)alloc((size_t)QKVN * DMODEL * 2);
  unsigned short* wot   = (unsigned short*)alloc((size_t)DMODEL * DMODEL * 2);
  unsigned short* w1t   = (unsigned short*)alloc((size_t)HID * DMODEL * 2);
  unsigned short* w2t   = (unsigned short*)alloc((size_t)DMODEL * HID * 2);
  float*          bqkv  = (float*)alloc((size_t)QKVN * 4);
  unsigned short* xb    = (unsigned short*)alloc((size_t)TOK * DMODEL * 2);
  unsigned short* qkvb  = (unsigned short*)alloc((size_t)TOK * QKVN * 2);
  unsigned short* vtb   = (unsigned short*)alloc((size_t)NBH * 64 * SPAD * 2);
  unsigned short* Pb    = (unsigned short*)alloc((size_t)NBH * SROW * SPAD * 2);
  unsigned short* aob   = (unsigned short*)alloc((size_t)TOK * DMODEL * 2);
  unsigned short* x1b   = (unsigned short*)alloc((size_t)TOK * DMODEL * 2);
  unsigned short* ctxb  = xb;   // alias: xb dead after QKV GEMM
  unsigned short* hb    = Pb;   // alias: P dead after attn_ctx (77.5MB <= 81.8MB)
  unsigned short* mob   = vtb;  // alias: vtb dead after attn_ctx (19.4MB <= 25.2MB)

  const int mtiles = (TOK + 127) / 128;  // 99

  cvt_x<<<(TOK * DMODEL / 4 + 255) / 256, 256, 0, stream>>>(x, xb, TOK * DMODEL);
  wt_t<<<dim3(DMODEL/32, DMODEL/32), 256, 0, stream>>>(Wq, wqkvt, DMODEL, DMODEL);
  wt_t<<<dim3(DMODEL/32, DMODEL/32), 256, 0, stream>>>(Wk, wqkvt + (size_t)DMODEL*DMODEL, DMODEL, DMODEL);
  wt_t<<<dim3(DMODEL/32, DMODEL/32), 256, 0, stream>>>(Wv, wqkvt + (size_t)2*DMODEL*DMODEL, DMODEL, DMODEL);
  wt_t<<<dim3(DMODEL/32, DMODEL/32), 256, 0, stream>>>(Wo, wot, DMODEL, DMODEL);
  wt_t<<<dim3(HID/32, DMODEL/32), 256, 0, stream>>>(W1, w1t, DMODEL, HID);
  wt_t<<<dim3(DMODEL/32, HID/32), 256, 0, stream>>>(W2, w2t, HID, DMODEL);
  cat_bias<<<9, 256, 0, stream>>>(bq, bk, bv, bqkv);

  gemm_nt<0><<<mtiles * (QKVN/128), 256, 0, stream>>>(xb, wqkvt, bqkv, qkvb, TOK, QKVN, DMODEL);
  attn_scores<<<NBH * 14, 256, 0, stream>>>(qkvb, Pb);
  softmax_k<<<NBH * SEQ / 4, 256, 0, stream>>>(Pb);
  vtrans<<<NBH, 256, 0, stream>>>(qkvb, vtb);
  attn_ctx<<<NBH * 4, 256, 0, stream>>>(Pb, vtb, ctxb);
  gemm_nt<0><<<mtiles * (DMODEL/128), 256, 0, stream>>>(ctxb, wot, bo, aob, TOK, DMODEL, DMODEL);
  ln_res<1,0><<<TOK / 4, 256, 0, stream>>>(aob, x, g1, be1, x1b);
  gemm_nt<1><<<mtiles * (HID/128), 256, 0, stream>>>(x1b, w1t, b1, hb, TOK, HID, DMODEL);
  gemm_nt<0><<<mtiles * (DMODEL/128), 256, 0, stream>>>(hb, w2t, b2, mob, TOK, DMODEL, HID);
  ln_res<0,1><<<TOK / 4, 256, 0, stream>>>(mob, x1b, g2, be2, d_out);
}

// Round 8
// 727.483 us; speedup vs baseline: 1.0325x; 1.0325x over previous
//
#include <hip/hip_runtime.h>
#include <hip/hip_bf16.h>
#include <math.h>

#define TOK   12608      // 64*197
#define DMODEL 768
#define QKVN  2304
#define HID   3072
#define NH    12
#define SEQ   197
#define SPAD  256        // padded t dimension
#define SROW  208        // padded s rows in P
#define NBH   768        // 64*12

typedef __attribute__((ext_vector_type(8))) __bf16 bf16x8;
typedef __attribute__((ext_vector_type(4))) float  f32x4;

__device__ __forceinline__ unsigned short f2b(float f){
  unsigned u = __builtin_bit_cast(unsigned, f);
  u += 0x7FFFu + ((u >> 16) & 1u);
  return (unsigned short)(u >> 16);
}
__device__ __forceinline__ float b2f(unsigned short h){
  unsigned u = ((unsigned)h) << 16;
  return __builtin_bit_cast(float, u);
}

#define GLD16(g, l) __builtin_amdgcn_global_load_lds( \
    (const __attribute__((address_space(1))) void*)(g), \
    (__attribute__((address_space(3))) void*)(l), 16, 0, 0)

// ---------------- fp32 -> bf16 elementwise ----------------
__global__ void cvt_x(const float* __restrict__ x, unsigned short* __restrict__ xb, int n){
  int idx = (blockIdx.x * blockDim.x + threadIdx.x) * 4;
  if (idx < n){
    float4 v = *reinterpret_cast<const float4*>(x + idx);
    ushort4 o; o.x = f2b(v.x); o.y = f2b(v.y); o.z = f2b(v.z); o.w = f2b(v.w);
    *reinterpret_cast<ushort4*>(xb + idx) = o;
  }
}

// ---------------- weight transpose + convert: W[K][N] f32 -> Wt[N][K] bf16 ----------------
__global__ void wt_t(const float* __restrict__ W, unsigned short* __restrict__ Wt, int K, int N){
  __shared__ float tile[32][33];
  int k0 = blockIdx.y * 32, n0 = blockIdx.x * 32;
  int tx = threadIdx.x & 31, ty = threadIdx.x >> 5;   // 256 threads: ty 0..7
#pragma unroll
  for (int i = 0; i < 32; i += 8)
    tile[ty + i][tx] = W[(size_t)(k0 + ty + i) * N + n0 + tx];
  __syncthreads();
#pragma unroll
  for (int i = 0; i < 32; i += 8)
    Wt[(size_t)(n0 + ty + i) * K + k0 + tx] = f2b(tile[tx][ty + i]);
}

__global__ void cat_bias(const float* __restrict__ a, const float* __restrict__ b,
                         const float* __restrict__ c, float* __restrict__ o){
  int i = blockIdx.x * blockDim.x + threadIdx.x;
  if (i < 768) o[i] = a[i];
  else if (i < 1536) o[i] = b[i - 768];
  else if (i < 2304) o[i] = c[i - 1536];
}

// ---------------- main NT GEMM: C[M][N] = act(A[M,K] @ Wt[N,K]^T + bias) ----------------
// 128x128 tile, BK=32, 4 waves (2x2), 16x16x32 bf16 MFMA.
// Double-buffered LDS, prefetch-early (T3 minimum 2-phase): stage tile t+1
// BEFORE computing tile t; ONE __syncthreads per K-step (its implicit
// vmcnt(0)+lgkmcnt(0) drain is the recipe's "vmcnt(0); barrier").
template<int ACT>
__global__ __launch_bounds__(256)
void gemm_nt(const unsigned short* __restrict__ A,
             const unsigned short* __restrict__ Bt,
             const float* __restrict__ bias,
             unsigned short* __restrict__ C,
             int M, int N, int K)
{
  __shared__ unsigned short As[2][128 * 32];
  __shared__ unsigned short Bs[2][128 * 32];
  const int nb = N >> 7;
  const int bm = blockIdx.x / nb;
  const int bn = blockIdx.x - bm * nb;
  const int m0 = bm << 7, n0 = bn << 7;
  const int tid = threadIdx.x;
  const int lane = tid & 63;
  const int wid = tid >> 6;

  // staging: thread tid covers row r=tid>>2, k-part (tid&3)*8 (16B)
  const int r  = tid >> 2;
  const int kk = (tid & 3) << 3;
  const unsigned short* gA1 = A  + (size_t)min(m0 + r,      M - 1) * K + kk;
  const unsigned short* gA2 = A  + (size_t)min(m0 + r + 64, M - 1) * K + kk;
  const unsigned short* gB1 = Bt + (size_t)(n0 + r)      * K + kk;
  const unsigned short* gB2 = Bt + (size_t)(n0 + r + 64) * K + kk;

  const int fr = lane & 15;
  const int kg = (lane >> 4) << 3;
  const int wm = (wid >> 1) << 6;
  const int wn = (wid & 1) << 6;

  f32x4 acc[4][4] = {};

  const int nk = K >> 5;   // K-steps of 32

  // prologue: stage tile 0 into buf 0
  {
    char* ldsA = (char*)As[0] + wid * 1024;
    char* ldsB = (char*)Bs[0] + wid * 1024;
    GLD16(gA1, ldsA);
    GLD16(gA2, ldsA + 4096);
    GLD16(gB1, ldsB);
    GLD16(gB2, ldsB + 4096);
  }
  __syncthreads();   // vmcnt(0) drain + barrier

  int cur = 0;
  for (int it = 0; it < nk; ++it){
    // 1) issue next tile's loads FIRST (latency hides under compute below)
    if (it + 1 < nk){
      const int ktn = (it + 1) << 5;
      char* ldsA = (char*)As[cur ^ 1] + wid * 1024;
      char* ldsB = (char*)Bs[cur ^ 1] + wid * 1024;
      GLD16(gA1 + ktn, ldsA);
      GLD16(gA2 + ktn, ldsA + 4096);
      GLD16(gB1 + ktn, ldsB);
      GLD16(gB2 + ktn, ldsB + 4096);
    }

    // 2) compute current tile from buf[cur]
    bf16x8 af[4], bfv[4];
#pragma unroll
    for (int i = 0; i < 4; i++)
      af[i]  = *reinterpret_cast<const bf16x8*>(&As[cur][(wm + i * 16 + fr) * 32 + kg]);
#pragma unroll
    for (int i = 0; i < 4; i++)
      bfv[i] = *reinterpret_cast<const bf16x8*>(&Bs[cur][(wn + i * 16 + fr) * 32 + kg]);
#pragma unroll
    for (int mi = 0; mi < 4; mi++)
#pragma unroll
      for (int ni = 0; ni < 4; ni++)
        acc[mi][ni] = __builtin_amdgcn_mfma_f32_16x16x32_bf16(af[mi], bfv[ni], acc[mi][ni], 0, 0, 0);

    // 3) one barrier per K-step: drains stage (vmcnt) + reads (lgkm), then syncs
    __syncthreads();
    cur ^= 1;
  }

  const int rbase = m0 + wm + ((lane >> 4) << 2);
#pragma unroll
  for (int ni = 0; ni < 4; ni++){
    const int cc = n0 + wn + ni * 16 + fr;
    const float bv = bias[cc];
#pragma unroll
    for (int mi = 0; mi < 4; mi++){
      const int rr0 = rbase + mi * 16;
#pragma unroll
      for (int j = 0; j < 4; j++){
        int rr = rr0 + j;
        if (rr < M){
          float v = acc[mi][ni][j] + bv;
          if (ACT == 1) v = 0.5f * v * (1.0f + erff(v * 0.70710678118f));
          C[(size_t)rr * N + cc] = f2b(v);
        }
      }
    }
  }
}

// ---------------- attention scores: P[bh][s][t] = (q . k) * 0.125, bf16 ----------------
// grid = NBH * 7(mtiles of 32) * 2(ntiles of 128); 4 waves 2x2, wave tile 16x64, K=64
__global__ __launch_bounds__(256)
void attn_scores(const unsigned short* __restrict__ qkv, unsigned short* __restrict__ P)
{
  const int gid = blockIdx.x;
  const int nt = gid & 1;
  const int mt = (gid >> 1) % 7;
  const int bh = gid / 14;
  const int b = bh / NH, h = bh - b * NH;
  const int lane = threadIdx.x & 63, wid = threadIdx.x >> 6;
  const int m0 = mt * 32 + (wid >> 1) * 16;
  const int n0 = nt * 128 + (wid & 1) * 64;
  const size_t qbase = (size_t)b * SEQ * QKVN + h * 64;
  const size_t kbase = qbase + 768;
  const int fr = lane & 15;
  const int kg = (lane >> 4) << 3;
  const int ar = min(m0 + fr, SEQ - 1);

  f32x4 acc[4] = {};
#pragma unroll
  for (int ks = 0; ks < 64; ks += 32){
    bf16x8 af = *reinterpret_cast<const bf16x8*>(&qkv[qbase + (size_t)ar * QKVN + ks + kg]);
#pragma unroll
    for (int ni = 0; ni < 4; ni++){
      int t = min(n0 + ni * 16 + fr, SEQ - 1);
      bf16x8 bv = *reinterpret_cast<const bf16x8*>(&qkv[kbase + (size_t)t * QKVN + ks + kg]);
      acc[ni] = __builtin_amdgcn_mfma_f32_16x16x32_bf16(af, bv, acc[ni], 0, 0, 0);
    }
  }
  const int rbase = m0 + ((lane >> 4) << 2);
#pragma unroll
  for (int ni = 0; ni < 4; ni++){
    int cc = n0 + ni * 16 + fr;
#pragma unroll
    for (int j = 0; j < 4; j++){
      int rr = rbase + j;
      if (rr < SEQ)
        P[((size_t)bh * SROW + rr) * SPAD + cc] = f2b(acc[ni][j] * 0.125f);
    }
  }
}

// ---------------- softmax: one wave per row, 256 cols (197 valid) ----------------
__global__ __launch_bounds__(256)
void softmax_k(unsigned short* __restrict__ P)
{
  const int idx = blockIdx.x * 4 + (threadIdx.x >> 6);
  const int bh = idx / SEQ;
  const int s  = idx - bh * SEQ;
  unsigned short* p = P + ((size_t)bh * SROW + s) * SPAD;
  const int lane = threadIdx.x & 63;
  float v[4];
  ushort4 u = *reinterpret_cast<const ushort4*>(p + lane * 4);
  v[0] = b2f(u.x); v[1] = b2f(u.y); v[2] = b2f(u.z); v[3] = b2f(u.w);
  float m = -1e30f;
#pragma unroll
  for (int j = 0; j < 4; j++){
    if (lane * 4 + j < SEQ) m = fmaxf(m, v[j]); else v[j] = -1e30f;
  }
#pragma unroll
  for (int o = 32; o > 0; o >>= 1) m = fmaxf(m, __shfl_xor(m, o));
  float sum = 0.f;
#pragma unroll
  for (int j = 0; j < 4; j++){ v[j] = __expf(v[j] - m); sum += v[j]; }
#pragma unroll
  for (int o = 32; o > 0; o >>= 1) sum += __shfl_xor(sum, o);
  const float inv = 1.0f / sum;
  ushort4 o4;
  o4.x = f2b(v[0] * inv); o4.y = f2b(v[1] * inv);
  o4.z = f2b(v[2] * inv); o4.w = f2b(v[3] * inv);
  *reinterpret_cast<ushort4*>(p + lane * 4) = o4;
}

// ---------------- V transpose per head: VT[bh][d][t] (t padded 256, zeros) ----------------
__global__ __launch_bounds__(256)
void vtrans(const unsigned short* __restrict__ qkv, unsigned short* __restrict__ VT)
{
  const int bh = blockIdx.x;
  const int b = bh / NH, h = bh - b * NH;
  __shared__ unsigned short t[SROW][66];
  const size_t vbase = (size_t)b * SEQ * QKVN + 1536 + h * 64;
  const int lane = threadIdx.x & 63, wid = threadIdx.x >> 6;
  for (int s = wid; s < SROW; s += 4){
    unsigned short val = 0;
    if (s < SEQ) val = qkv[vbase + (size_t)s * QKVN + lane];
    t[s][lane] = val;
  }
  __syncthreads();
  unsigned short* o = VT + (size_t)bh * 64 * SPAD;
  const int tid = threadIdx.x;
#pragma unroll
  for (int i = 0; i < 64; i++){
    int idx = tid + i * 256;
    int d = idx >> 8, tt = idx & 255;
    o[idx] = (tt < SROW) ? t[tt][d] : (unsigned short)0;
  }
}

// ---------------- ctx: C[b,s,(h,d)] = P[bh] @ V[bh]  (M=197,N=64,K=256) ----------------
// grid = NBH * 4(mtiles of 64); wave w handles rows m0+w*16, all 64 cols
__global__ __launch_bounds__(256)
void attn_ctx(const unsigned short* __restrict__ P,
              const unsigned short* __restrict__ VT,
              unsigned short* __restrict__ ctx)
{
  const int mt = blockIdx.x & 3;
  const int bh = blockIdx.x >> 2;
  const int b = bh / NH, h = bh - b * NH;
  const int lane = threadIdx.x & 63, wid = threadIdx.x >> 6;
  const int m0 = mt * 64 + wid * 16;
  const unsigned short* Pr = P  + (size_t)bh * SROW * SPAD;
  const unsigned short* Vr = VT + (size_t)bh * 64 * SPAD;
  const int fr = lane & 15;
  const int kg = (lane >> 4) << 3;
  const int ar = min(m0 + fr, SEQ - 1);

  f32x4 acc[4] = {};
#pragma unroll
  for (int ks = 0; ks < SPAD; ks += 32){
    bf16x8 af = *reinterpret_cast<const bf16x8*>(&Pr[(size_t)ar * SPAD + ks + kg]);
#pragma unroll
    for (int ni = 0; ni < 4; ni++){
      bf16x8 bv = *reinterpret_cast<const bf16x8*>(&Vr[(size_t)(ni * 16 + fr) * SPAD + ks + kg]);
      acc[ni] = __builtin_amdgcn_mfma_f32_16x16x32_bf16(af, bv, acc[ni], 0, 0, 0);
    }
  }
  const int rbase = m0 + ((lane >> 4) << 2);
#pragma unroll
  for (int ni = 0; ni < 4; ni++){
    int d = ni * 16 + fr;
#pragma unroll
    for (int j = 0; j < 4; j++){
      int rr = rbase + j;
      if (rr < SEQ)
        ctx[((size_t)b * SEQ + rr) * DMODEL + h * 64 + d] = f2b(acc[ni][j]);
    }
  }
}

// ---------------- residual + LayerNorm: out = res + LN(y)*g + be ----------------
// one wave per row (64 lanes x 12 elems = 768)
// RESF32: residual input is f32.  OUTF32: write f32 output (final kernel -> d_out).
template<int RESF32, int OUTF32>
__global__ __launch_bounds__(256)
void ln_res(const unsigned short* __restrict__ y,
            const void* __restrict__ res,
            const float* __restrict__ g,
            const float* __restrict__ be,
            void* __restrict__ out)
{
  const int row = blockIdx.x * 4 + (threadIdx.x >> 6);
  const int lane = threadIdx.x & 63;
  const int c0 = lane * 12;
  const unsigned short* yr = y + (size_t)row * DMODEL + c0;
  float v[12];
#pragma unroll
  for (int i = 0; i < 3; i++){
    ushort4 u = *reinterpret_cast<const ushort4*>(yr + i * 4);
    v[i*4+0] = b2f(u.x); v[i*4+1] = b2f(u.y); v[i*4+2] = b2f(u.z); v[i*4+3] = b2f(u.w);
  }
  float s = 0.f;
#pragma unroll
  for (int i = 0; i < 12; i++) s += v[i];
#pragma unroll
  for (int o = 32; o > 0; o >>= 1) s += __shfl_xor(s, o);
  const float mu = s * (1.0f / 768.0f);
  float vs = 0.f;
#pragma unroll
  for (int i = 0; i < 12; i++){ float d = v[i] - mu; vs += d * d; }
#pragma unroll
  for (int o = 32; o > 0; o >>= 1) vs += __shfl_xor(vs, o);
  const float rstd = rsqrtf(vs * (1.0f / 768.0f) + 1e-6f);
  float ov[12];
#pragma unroll
  for (int i = 0; i < 12; i++){
    float rv;
    if (RESF32) rv = ((const float*)res)[(size_t)row * DMODEL + c0 + i];
    else        rv = b2f(((const unsigned short*)res)[(size_t)row * DMODEL + c0 + i]);
    ov[i] = (v[i] - mu) * rstd * g[c0 + i] + be[c0 + i] + rv;
  }
  if (OUTF32){
    float* o = (float*)out + (size_t)row * DMODEL + c0;
#pragma unroll
    for (int i = 0; i < 3; i++)
      *reinterpret_cast<float4*>(o + i * 4) = *reinterpret_cast<float4*>(&ov[i * 4]);
  } else {
    unsigned short* o = (unsigned short*)out + (size_t)row * DMODEL + c0;
    unsigned short ob[12];
#pragma unroll
    for (int i = 0; i < 12; i++) ob[i] = f2b(ov[i]);
#pragma unroll
    for (int i = 0; i < 3; i++)
      *reinterpret_cast<ushort4*>(o + i * 4) = *reinterpret_cast<ushort4*>(&ob[i * 4]);
  }
}

// ---------------- host ----------------
extern "C" void kernel_launch(void* const* d_in, const int* in_sizes, int n_in,
                              void* d_out, int out_size, void* d_ws, size_t ws_size,
                              hipStream_t stream)
{
  const float* x   = (const float*)d_in[0];
  const float* Wq  = (const float*)d_in[1];
  const float* bq  = (const float*)d_in[2];
  const float* Wk  = (const float*)d_in[3];
  const float* bk  = (const float*)d_in[4];
  const float* Wv  = (const float*)d_in[5];
  const float* bv  = (const float*)d_in[6];
  const float* Wo  = (const float*)d_in[7];
  const float* bo  = (const float*)d_in[8];
  const float* W1  = (const float*)d_in[9];
  const float* b1  = (const float*)d_in[10];
  const float* W2  = (const float*)d_in[11];
  const float* b2  = (const float*)d_in[12];
  const float* g1  = (const float*)d_in[13];
  const float* be1 = (const float*)d_in[14];
  const float* g2  = (const float*)d_in[15];
  const float* be2 = (const float*)d_in[16];

  char* w = (char*)d_ws;
  size_t off = 0;
  auto alloc = [&](size_t bytes){ void* p = w + off; off = (off + bytes + 255) & ~(size_t)255; return p; };
  unsigned short* wqkvt = (unsigned short*)alloc((size_t)QKVN * DMODEL * 2);
  unsigned short* wot   = (unsigned short*)alloc((size_t)DMODEL * DMODEL * 2);
  unsigned short* w1t   = (unsigned short*)alloc((size_t)HID * DMODEL * 2);
  unsigned short* w2t   = (unsigned short*)alloc((size_t)DMODEL * HID * 2);
  float*          bqkv  = (float*)alloc((size_t)QKVN * 4);
  unsigned short* xb    = (unsigned short*)alloc((size_t)TOK * DMODEL * 2);
  unsigned short* qkvb  = (unsigned short*)alloc((size_t)TOK * QKVN * 2);
  unsigned short* vtb   = (unsigned short*)alloc((size_t)NBH * 64 * SPAD * 2);
  unsigned short* Pb    = (unsigned short*)alloc((size_t)NBH * SROW * SPAD * 2);
  unsigned short* aob   = (unsigned short*)alloc((size_t)TOK * DMODEL * 2);
  unsigned short* x1b   = (unsigned short*)alloc((size_t)TOK * DMODEL * 2);
  unsigned short* ctxb  = xb;   // alias: xb dead after QKV GEMM
  unsigned short* hb    = Pb;   // alias: P dead after attn_ctx (77.5MB <= 81.8MB)
  unsigned short* mob   = vtb;  // alias: vtb dead after attn_ctx (19.4MB <= 25.2MB)

  const int mtiles = (TOK + 127) / 128;  // 99

  cvt_x<<<(TOK * DMODEL / 4 + 255) / 256, 256, 0, stream>>>(x, xb, TOK * DMODEL);
  wt_t<<<dim3(DMODEL/32, DMODEL/32), 256, 0, stream>>>(Wq, wqkvt, DMODEL, DMODEL);
  wt_t<<<dim3(DMODEL/32, DMODEL/32), 256, 0, stream>>>(Wk, wqkvt + (size_t)DMODEL*DMODEL, DMODEL, DMODEL);
  wt_t<<<dim3(DMODEL/32, DMODEL/32), 256, 0, stream>>>(Wv, wqkvt + (size_t)2*DMODEL*DMODEL, DMODEL, DMODEL);
  wt_t<<<dim3(DMODEL/32, DMODEL/32), 256, 0, stream>>>(Wo, wot, DMODEL, DMODEL);
  wt_t<<<dim3(HID/32, DMODEL/32), 256, 0, stream>>>(W1, w1t, DMODEL, HID);
  wt_t<<<dim3(DMODEL/32, HID/32), 256, 0, stream>>>(W2, w2t, HID, DMODEL);
  cat_bias<<<9, 256, 0, stream>>>(bq, bk, bv, bqkv);

  gemm_nt<0><<<mtiles * (QKVN/128), 256, 0, stream>>>(xb, wqkvt, bqkv, qkvb, TOK, QKVN, DMODEL);
  attn_scores<<<NBH * 14, 256, 0, stream>>>(qkvb, Pb);
  softmax_k<<<NBH * SEQ / 4, 256, 0, stream>>>(Pb);
  vtrans<<<NBH, 256, 0, stream>>>(qkvb, vtb);
  attn_ctx<<<NBH * 4, 256, 0, stream>>>(Pb, vtb, ctxb);
  gemm_nt<0><<<mtiles * (DMODEL/128), 256, 0, stream>>>(ctxb, wot, bo, aob, TOK, DMODEL, DMODEL);
  ln_res<1,0><<<TOK / 4, 256, 0, stream>>>(aob, x, g1, be1, x1b);
  gemm_nt<1><<<mtiles * (HID/128), 256, 0, stream>>>(x1b, w1t, b1, hb, TOK, HID, DMODEL);
  gemm_nt<0><<<mtiles * (DMODEL/128), 256, 0, stream>>>(hb, w2t, b2, mob, TOK, DMODEL, HID);
  ln_res<0,1><<<TOK / 4, 256, 0, stream>>>(mob, x1b, g2, be2, d_out);
}